// Round 5
// baseline (1165.380 us; speedup 1.0000x reference)
//
#include <hip/hip_runtime.h>
#include <math.h>

// Problem constants (reference: MAB block, B=4, N=1024, D=1024, H=16)
#define BATCH 4
#define NQL   1024
#define NKL   1024
#define DIM   1024
#define NHEAD 16
#define DHEAD 64
#define MROWS 4096          // BATCH*NQL
#define SCALE 0.03125f      // 1/sqrt(DIM)

typedef float  f32x4  __attribute__((ext_vector_type(4)));
typedef short  short8 __attribute__((ext_vector_type(8)));

// bf16 (bit-level, RNE) helpers — self-consistent, no __bf16 type dependence
__device__ __forceinline__ ushort f2bf(float x) {
    uint u = __float_as_uint(x);
    u += 0x7FFFu + ((u >> 16) & 1u);
    return (ushort)(u >> 16);
}
__device__ __forceinline__ float bf2f(ushort h) {
    return __uint_as_float(((uint)h) << 16);
}

// ===========================================================================
// split_bf: x (fp32) -> hi = bf16(x), lo = bf16(x - hi).  n4 = n/4.
// ===========================================================================
__global__ __launch_bounds__(256)
void split_bf(const float* __restrict__ x, ushort* __restrict__ hi,
              ushort* __restrict__ lo, int n4)
{
    const int i = blockIdx.x * 256 + threadIdx.x;
    if (i >= n4) return;
    const float4 v = ((const float4*)x)[i];
    ushort4 h, l;
    h.x = f2bf(v.x); l.x = f2bf(v.x - bf2f(h.x));
    h.y = f2bf(v.y); l.y = f2bf(v.y - bf2f(h.y));
    h.z = f2bf(v.z); l.z = f2bf(v.z - bf2f(h.z));
    h.w = f2bf(v.w); l.w = f2bf(v.w - bf2f(h.w));
    ((ushort4*)hi)[i] = h;
    ((ushort4*)lo)[i] = l;
}

// ===========================================================================
// gemm_mfma: C[m,n] = scale * sum_k A[m,k]*B[n,k]  (NT; both operands bf16-
// split row-major, k contiguous) + optional bias[n] + residual R[m,n].
//   NPROD=3: D += Ahi*Bhi + Ahi*Blo + Alo*Bhi  (fp32-grade)
//   NPROD=1: D += Ahi*Bhi                       (scores)
// 128x128 tile, 4 waves (2x2 of 64x64), BK=32, mfma_f32_16x16x32_bf16.
// LDS tiles [128][32] bf16 (64B rows): frag ds_read_b128 = 1KB contiguous
// per wave -> conflict-free. Reg-staged double buffer, 1 barrier/K-step.
// C/D layout (m89-verified): col = lane&15, row = (lane>>4)*4 + reg.
// Batched via blockIdx.z -> (zh=z/ZB, zb=z%ZB).
// ===========================================================================
template<int NPROD, int BIAS, int RESID, int OUTHI>
__global__ __launch_bounds__(256)
void gemm_mfma(const ushort* __restrict__ Ahi, const ushort* __restrict__ Alo,
               int lda, long aBs, long aHs,
               const ushort* __restrict__ Bhi, const ushort* __restrict__ Blo,
               int ldb, long bBs, long bHs,
               const float* __restrict__ bias,
               const float* __restrict__ rm, long rBs, long rHs,
               float* __restrict__ Cm, ushort* __restrict__ Chi,
               int ldc, long cBs, long cHs,
               int Kd, float scale, int ZB)
{
    constexpr int NT_ = (NPROD == 3) ? 4 : 2;   // tiles: Ahi,Bhi[,Alo,Blo]
    __shared__ ushort lds[2][NT_][128 * 32];

    const int tid  = threadIdx.x;
    const int lane = tid & 63;
    const int wid  = tid >> 6;
    const int wr   = wid >> 1, wc = wid & 1;    // wave's 64x64 sub-tile
    const int bm   = blockIdx.x * 128;
    const int bn   = blockIdx.y * 128;

    const int zz = blockIdx.z;
    const int zh = zz / ZB, zb = zz % ZB;
    Ahi += (size_t)zb * aBs + (size_t)zh * aHs;
    Bhi += (size_t)zb * bBs + (size_t)zh * bHs;
    Cm  += (size_t)zb * cBs + (size_t)zh * cHs;
    const float* Rm = nullptr;
    if (RESID) Rm = rm + (size_t)zb * rBs + (size_t)zh * rHs;

    const ushort* tb[NT_];
    int tldv[NT_];
    tb[0] = Ahi + (size_t)bm * lda;  tldv[0] = lda;
    tb[1] = Bhi + (size_t)bn * ldb;  tldv[1] = ldb;
    if constexpr (NPROD == 3) {
        tb[2] = Alo + (size_t)zb * aBs + (size_t)zh * aHs + (size_t)bm * lda;  tldv[2] = lda;
        tb[3] = Blo + (size_t)zb * bBs + (size_t)zh * bHs + (size_t)bn * ldb;  tldv[3] = ldb;
    }

    int4 rg[NT_][2];
    auto gload = [&](int k0) {
#pragma unroll
        for (int tt = 0; tt < NT_; ++tt)
#pragma unroll
            for (int p = 0; p < 2; ++p) {
                const int idx = p * 256 + tid;           // 0..511 16B-chunks
                rg[tt][p] = *(const int4*)(tb[tt] + (size_t)(idx >> 2) * tldv[tt]
                                           + k0 + ((idx & 3) << 3));
            }
    };
    auto dswrite = [&](int buf) {
#pragma unroll
        for (int tt = 0; tt < NT_; ++tt)
#pragma unroll
            for (int p = 0; p < 2; ++p)
                *(int4*)&lds[buf][tt][(size_t)(p * 256 + tid) * 8] = rg[tt][p];
    };

    // prologue: stage K-tile 0
    gload(0);
    dswrite(0);
    __syncthreads();

    f32x4 acc[4][4] = {};
    int cur = 0;
    const int nt = Kd >> 5;

    const int rA = wr * 64 + (lane & 15);
    const int rB = wc * 64 + (lane & 15);
    const int kg = (lane >> 4) << 3;

    for (int t = 0; t < nt; ++t) {
        const bool more = (t + 1) < nt;
        if (more) gload((t + 1) << 5);     // issue next-tile loads early

        short8 ah[4], bh[4], al[4], bl[4];
#pragma unroll
        for (int f = 0; f < 4; ++f) {
            ah[f] = *(const short8*)&lds[cur][0][(size_t)(rA + f * 16) * 32 + kg];
            bh[f] = *(const short8*)&lds[cur][1][(size_t)(rB + f * 16) * 32 + kg];
        }
        if constexpr (NPROD == 3) {
#pragma unroll
            for (int f = 0; f < 4; ++f) {
                al[f] = *(const short8*)&lds[cur][2][(size_t)(rA + f * 16) * 32 + kg];
                bl[f] = *(const short8*)&lds[cur][3][(size_t)(rB + f * 16) * 32 + kg];
            }
        }

#pragma unroll
        for (int fi = 0; fi < 4; ++fi)
#pragma unroll
            for (int fj = 0; fj < 4; ++fj) {
                acc[fi][fj] = __builtin_amdgcn_mfma_f32_16x16x32_bf16(ah[fi], bh[fj], acc[fi][fj], 0, 0, 0);
                if constexpr (NPROD == 3) {
                    acc[fi][fj] = __builtin_amdgcn_mfma_f32_16x16x32_bf16(ah[fi], bl[fj], acc[fi][fj], 0, 0, 0);
                    acc[fi][fj] = __builtin_amdgcn_mfma_f32_16x16x32_bf16(al[fi], bh[fj], acc[fi][fj], 0, 0, 0);
                }
            }

        if (more) dswrite(cur ^ 1);  // other buffer: no conflict with readers
        __syncthreads();             // single barrier per K-step
        cur ^= 1;
    }

    // epilogue
    float biasv[4];
    if (BIAS) {
#pragma unroll
        for (int fj = 0; fj < 4; ++fj)
            biasv[fj] = bias[bn + wc * 64 + fj * 16 + (lane & 15)];
    }
#pragma unroll
    for (int fi = 0; fi < 4; ++fi) {
        const int r0 = bm + wr * 64 + fi * 16 + ((lane >> 4) << 2);
#pragma unroll
        for (int fj = 0; fj < 4; ++fj) {
            const int c = bn + wc * 64 + fj * 16 + (lane & 15);
#pragma unroll
            for (int r = 0; r < 4; ++r) {
                float o = acc[fi][fj][r] * scale;
                if (BIAS) o += biasv[fj];
                if (RESID) o += Rm[(size_t)(r0 + r) * ldc + c];
                Cm[(size_t)(r0 + r) * ldc + c] = o;
                if (OUTHI) Chi[(size_t)(r0 + r) * ldc + c] = f2bf(o);
            }
        }
    }
}

// ===========================================================================
// fused_smax_pv: per block = (128 q-rows, one head-batch hb = h*4+b).
//   Pass 1: row max + inv-sum of exp over raw S row (1024).
//   Pass 2: normalize tile -> write P to global (the A output) -> LDS ->
//           accumulate O = Q + P*V (8x4 micro, fp32 VALU).
// Grid: (8, 1, 64). Exactly one block touches each A element.
// ===========================================================================
#define BT 128
#define LDB2 132

__global__ __launch_bounds__(256)
void fused_smax_pv(float* __restrict__ Aout,       // [64][1024][1024] S in, P out
                   const float* __restrict__ Vp,   // [4][1024][1024]
                   const float* __restrict__ Qp,   // [4][1024][1024] residual
                   float* __restrict__ Oa)         // [4][1024][1024]
{
    __shared__ float As[16][LDB2];    // P tile, k-major
    __shared__ float Bs[16][68];      // V tile
    __shared__ float sm_m[128], sm_li[128];

    const int tid  = threadIdx.x;
    const int lane = tid & 63;
    const int wv   = tid >> 6;
    const int bm   = blockIdx.x * BT;
    const int z    = blockIdx.z;
    const int zh   = z >> 2, zb = z & 3;

    float* Ab       = Aout + (size_t)z * (1u << 20) + (size_t)bm * NKL;
    const float* Vb = Vp + (size_t)zb * (1u << 20) + (size_t)zh * DHEAD;
    const float* Qb = Qp + (size_t)zb * (1u << 20) + (size_t)zh * DHEAD + (size_t)bm * DIM;
    float* Ob       = Oa + (size_t)zb * (1u << 20) + (size_t)zh * DHEAD + (size_t)bm * DIM;

    // ---- pass 1 ----
    for (int r = wv; r < BT; r += 4) {
        const float* p = Ab + (size_t)r * NKL + (lane << 2);
        float4 x0 = *(const float4*)(p);
        float4 x1 = *(const float4*)(p + 256);
        float4 x2 = *(const float4*)(p + 512);
        float4 x3 = *(const float4*)(p + 768);
        float m = fmaxf(fmaxf(fmaxf(x0.x, x0.y), fmaxf(x0.z, x0.w)),
                        fmaxf(fmaxf(x1.x, x1.y), fmaxf(x1.z, x1.w)));
        m = fmaxf(m, fmaxf(fmaxf(fmaxf(x2.x, x2.y), fmaxf(x2.z, x2.w)),
                           fmaxf(fmaxf(x3.x, x3.y), fmaxf(x3.z, x3.w))));
#pragma unroll
        for (int off = 32; off; off >>= 1) m = fmaxf(m, __shfl_xor(m, off));
        float s = __expf(x0.x - m) + __expf(x0.y - m) + __expf(x0.z - m) + __expf(x0.w - m)
                + __expf(x1.x - m) + __expf(x1.y - m) + __expf(x1.z - m) + __expf(x1.w - m)
                + __expf(x2.x - m) + __expf(x2.y - m) + __expf(x2.z - m) + __expf(x2.w - m)
                + __expf(x3.x - m) + __expf(x3.y - m) + __expf(x3.z - m) + __expf(x3.w - m);
#pragma unroll
        for (int off = 32; off; off >>= 1) s += __shfl_xor(s, off);
        if (lane == 0) { sm_m[r] = m; sm_li[r] = 1.f / s; }
    }
    __syncthreads();

    const float m0  = sm_m[tid >> 2],  m1  = sm_m[(tid >> 2) + 64];
    const float li0 = sm_li[tid >> 2], li1 = sm_li[(tid >> 2) + 64];

    // ---- pass 2 ----
    const int tx = tid & 15;
    const int ty = tid >> 4;
    const int lrow = tid >> 2;
    const int lk4  = (tid & 3) << 2;
    const int bkk  = tid >> 4;
    const int bn0  = (tid & 15) << 2;

    float acc[8][4] = {};

    float* Ap0 = Ab + (size_t)lrow * NKL + lk4;
    float* Ap1 = Ab + (size_t)(lrow + 64) * NKL + lk4;
    const float* Vpp = Vb + (size_t)bkk * DIM + bn0;

    float4 a0v = *(const float4*)(Ap0);
    float4 a1v = *(const float4*)(Ap1);
    float4 bvv = *(const float4*)(Vpp);

    for (int k0 = 0; k0 < NKL; k0 += 16) {
        float4 p0, p1;
        p0.x = __expf(a0v.x - m0) * li0;  p0.y = __expf(a0v.y - m0) * li0;
        p0.z = __expf(a0v.z - m0) * li0;  p0.w = __expf(a0v.w - m0) * li0;
        p1.x = __expf(a1v.x - m1) * li1;  p1.y = __expf(a1v.y - m1) * li1;
        p1.z = __expf(a1v.z - m1) * li1;  p1.w = __expf(a1v.w - m1) * li1;
        *(float4*)(Ap0 + k0) = p0;
        *(float4*)(Ap1 + k0) = p1;

        __syncthreads();
        As[lk4 + 0][lrow] = p0.x;  As[lk4 + 1][lrow] = p0.y;
        As[lk4 + 2][lrow] = p0.z;  As[lk4 + 3][lrow] = p0.w;
        As[lk4 + 0][lrow + 64] = p1.x;  As[lk4 + 1][lrow + 64] = p1.y;
        As[lk4 + 2][lrow + 64] = p1.z;  As[lk4 + 3][lrow + 64] = p1.w;
        *(float4*)&Bs[bkk][bn0] = bvv;
        __syncthreads();

        if (k0 + 16 < NKL) {
            a0v = *(const float4*)(Ap0 + k0 + 16);
            a1v = *(const float4*)(Ap1 + k0 + 16);
            bvv = *(const float4*)(Vpp + (size_t)(k0 + 16) * DIM);
        }

#pragma unroll
        for (int kk = 0; kk < 16; ++kk) {
            const float4 a0 = *(const float4*)&As[kk][ty << 3];
            const float4 a1 = *(const float4*)&As[kk][(ty << 3) + 4];
            const float4 b  = *(const float4*)&Bs[kk][tx << 2];
            const float aa[8] = {a0.x, a0.y, a0.z, a0.w, a1.x, a1.y, a1.z, a1.w};
            const float bb[4] = {b.x, b.y, b.z, b.w};
#pragma unroll
            for (int i = 0; i < 8; ++i)
#pragma unroll
                for (int j = 0; j < 4; ++j)
                    acc[i][j] = fmaf(aa[i], bb[j], acc[i][j]);
        }
    }

#pragma unroll
    for (int i = 0; i < 8; ++i) {
        const size_t idx = (size_t)((ty << 3) + i) * DIM + (tx << 2);
        const float4 q = *(const float4*)(Qb + idx);
        float4 v = make_float4(acc[i][0] + q.x, acc[i][1] + q.y,
                               acc[i][2] + q.z, acc[i][3] + q.w);
        *(float4*)(Ob + idx) = v;
    }
}

// ===========================================================================
// Row LayerNorm (1024 cols, one block/row). SPLIT=1 also emits bf16 hi/lo.
// ===========================================================================
template<int SPLIT>
__global__ __launch_bounds__(256)
void ln_rows(const float* __restrict__ in, const float* __restrict__ g,
             const float* __restrict__ b, float* __restrict__ out,
             ushort* __restrict__ ohi, ushort* __restrict__ olo)
{
    const int row = blockIdx.x;
    const int tid = threadIdx.x;
    const float4 xv = *(const float4*)(in + (size_t)row * DIM + (tid << 2));

    float s = xv.x + xv.y + xv.z + xv.w;
    float q = xv.x * xv.x + xv.y * xv.y + xv.z * xv.z + xv.w * xv.w;
#pragma unroll
    for (int off = 32; off; off >>= 1) {
        s += __shfl_xor(s, off);
        q += __shfl_xor(q, off);
    }
    __shared__ float ss[4], qq[4];
    if ((tid & 63) == 0) { ss[tid >> 6] = s; qq[tid >> 6] = q; }
    __syncthreads();
    s = ss[0] + ss[1] + ss[2] + ss[3];
    q = qq[0] + qq[1] + qq[2] + qq[3];

    const float mu  = s * (1.f / 1024.f);
    const float var = q * (1.f / 1024.f) - mu * mu;
    const float rs  = rsqrtf(var + 1e-5f);

    const float4 gv = *(const float4*)(g + (tid << 2));
    const float4 bv = *(const float4*)(b + (tid << 2));
    float4 o;
    o.x = (xv.x - mu) * rs * gv.x + bv.x;
    o.y = (xv.y - mu) * rs * gv.y + bv.y;
    o.z = (xv.z - mu) * rs * gv.z + bv.z;
    o.w = (xv.w - mu) * rs * gv.w + bv.w;
    *(float4*)(out + (size_t)row * DIM + (tid << 2)) = o;

    if (SPLIT) {
        ushort4 h, l;
        h.x = f2bf(o.x); l.x = f2bf(o.x - bf2f(h.x));
        h.y = f2bf(o.y); l.y = f2bf(o.y - bf2f(h.y));
        h.z = f2bf(o.z); l.z = f2bf(o.z - bf2f(h.z));
        h.w = f2bf(o.w); l.w = f2bf(o.w - bf2f(h.w));
        ((ushort4*)(ohi + (size_t)row * DIM))[tid] = h;
        ((ushort4*)(olo + (size_t)row * DIM))[tid] = l;
    }
}

// ===========================================================================
// gate = silu(x1) * x2, emitted directly as bf16 hi/lo split.
// ===========================================================================
__global__ __launch_bounds__(256)
void silu_mul(const float* __restrict__ x12, ushort* __restrict__ ghi,
              ushort* __restrict__ glo)
{
    const int i = blockIdx.x * 256 + threadIdx.x;   // float4-group over [4096][1024]
    const int n = i >> 8;
    const int c = (i & 255) << 2;
    const float4 a = *(const float4*)(x12 + (size_t)n * 2048 + c);
    const float4 b = *(const float4*)(x12 + (size_t)n * 2048 + 1024 + c);
    float4 o;
    o.x = a.x / (1.f + __expf(-a.x)) * b.x;
    o.y = a.y / (1.f + __expf(-a.y)) * b.y;
    o.z = a.z / (1.f + __expf(-a.z)) * b.z;
    o.w = a.w / (1.f + __expf(-a.w)) * b.w;
    ushort4 h, l;
    h.x = f2bf(o.x); l.x = f2bf(o.x - bf2f(h.x));
    h.y = f2bf(o.y); l.y = f2bf(o.y - bf2f(h.y));
    h.z = f2bf(o.z); l.z = f2bf(o.z - bf2f(h.z));
    h.w = f2bf(o.w); l.w = f2bf(o.w - bf2f(h.w));
    ((ushort4*)ghi)[i] = h;
    ((ushort4*)glo)[i] = l;
}

// ---------------------------------------------------------------------------
extern "C" void kernel_launch(void* const* d_in, const int* in_sizes, int n_in,
                              void* d_out, int out_size, void* d_ws, size_t ws_size,
                              hipStream_t stream)
{
    const float* Q   = (const float*)d_in[0];
    const float* K   = (const float*)d_in[1];
    const float* Wq  = (const float*)d_in[2];
    const float* bq  = (const float*)d_in[3];
    const float* Wk  = (const float*)d_in[4];
    const float* bk  = (const float*)d_in[5];
    const float* Wv  = (const float*)d_in[6];
    const float* bv  = (const float*)d_in[7];
    const float* g0  = (const float*)d_in[8];
    const float* be0 = (const float*)d_in[9];
    const float* g1  = (const float*)d_in[10];
    const float* be1 = (const float*)d_in[11];
    const float* W12 = (const float*)d_in[12];
    const float* b12 = (const float*)d_in[13];
    const float* W3  = (const float*)d_in[14];
    const float* b3  = (const float*)d_in[15];

    // ws layout (needs 152 MiB). fp32 core 80MB, then bf16 split arrays.
    float* ws   = (float*)d_ws;
    float* Qp   = ws;                    // [4096,1024] fp32
    float* Kp   = ws + (1u << 22);
    float* Vp   = ws + (2u << 22);
    float* Oa   = ws + (3u << 22);
    float* Oln  = ws + (4u << 22);
    float* x12  = ws;                    // [4096,2048] overlays Qp,Kp (both dead)

    ushort* u     = (ushort*)(ws + (5u << 22));  // +80MB
    ushort* QpHi  = u;                   // 4M us each below
    ushort* KpHi  = u + (1u << 22);
    ushort* Qhi   = u + (2u << 22);
    ushort* Qlo   = u + (3u << 22);
    ushort* Khi   = u + (4u << 22);
    ushort* Klo   = u + (5u << 22);
    ushort* OlnHi = Qhi;                 // reuse (Q splits dead after proj)
    ushort* OlnLo = Qlo;
    ushort* GHi   = Khi;                 // gate splits reuse K splits
    ushort* GLo   = Klo;
    ushort* Wqhi  = u + (6u << 22);      // weights: 1M us each
    ushort* Wqlo  = Wqhi + (1u << 20);
    ushort* Wkhi  = Wqhi + (2u << 20);
    ushort* Wklo  = Wqhi + (3u << 20);
    ushort* Wvhi  = Wqhi + (4u << 20);
    ushort* Wvlo  = Wqhi + (5u << 20);
    ushort* W12hi = Wqhi + (6u << 20);   // 2M us
    ushort* W12lo = Wqhi + (8u << 20);
    ushort* W3hi  = Wqhi + (10u << 20);  // 1M us
    ushort* W3lo  = Wqhi + (11u << 20);

    float* Oout = (float*)d_out;                 // [4,1024,1024]
    float* Aout = Oout + (1u << 22);             // [64,1024,1024]

    const dim3 blk(256);
    const long MB1 = 1L << 20;
    const long MB4 = 4L << 20;

    // 0: split inputs + weights to bf16 hi/lo
    split_bf<<<4096, blk, 0, stream>>>(Q,   Qhi,   Qlo,   1 << 20);
    split_bf<<<4096, blk, 0, stream>>>(K,   Khi,   Klo,   1 << 20);
    split_bf<<<1024, blk, 0, stream>>>(Wq,  Wqhi,  Wqlo,  1 << 18);
    split_bf<<<1024, blk, 0, stream>>>(Wk,  Wkhi,  Wklo,  1 << 18);
    split_bf<<<1024, blk, 0, stream>>>(Wv,  Wvhi,  Wvlo,  1 << 18);
    split_bf<<<2048, blk, 0, stream>>>(W12, W12hi, W12lo, 1 << 19);
    split_bf<<<1024, blk, 0, stream>>>(W3,  W3hi,  W3lo,  1 << 18);

    // 1-3: projections (bf16x3 MFMA). Q/K also emit bf16-hi of the result.
    gemm_mfma<3,1,0,1><<<dim3(32,8,1), blk, 0, stream>>>(
        Qhi, Qlo, DIM, 0,0, Wqhi, Wqlo, DIM, 0,0, bq,
        nullptr, 0,0, Qp, QpHi, DIM, 0,0, DIM, 1.f, 1);
    gemm_mfma<3,1,0,1><<<dim3(32,8,1), blk, 0, stream>>>(
        Khi, Klo, DIM, 0,0, Wkhi, Wklo, DIM, 0,0, bk,
        nullptr, 0,0, Kp, KpHi, DIM, 0,0, DIM, 1.f, 1);
    gemm_mfma<3,1,0,0><<<dim3(32,8,1), blk, 0, stream>>>(
        Khi, Klo, DIM, 0,0, Wvhi, Wvlo, DIM, 0,0, bv,
        nullptr, 0,0, Vp, nullptr, DIM, 0,0, DIM, 1.f, 1);

    // 4: scores S = (Qh.Kh)/32 -> Aout[(h*4+b),q,k]  (hi-only MFMA, K=64)
    gemm_mfma<1,0,0,0><<<dim3(8,8,64), blk, 0, stream>>>(
        QpHi, nullptr, DIM, MB1, (long)DHEAD, KpHi, nullptr, DIM, MB1, (long)DHEAD,
        nullptr, nullptr, 0,0, Aout, nullptr, NKL, MB1, MB4, DHEAD, SCALE, BATCH);

    // 5: fused softmax + PV + residual (writes normalized A and Oa)
    fused_smax_pv<<<dim3(8,1,64), blk, 0, stream>>>(Aout, Vp, Qp, Oa);

    // 6: LN0 (+ split for FFN input)
    ln_rows<1><<<4096, blk, 0, stream>>>(Oa, g0, be0, Oln, OlnHi, OlnLo);

    // 7: x12 = Oln * W12^T + b12
    gemm_mfma<3,1,0,0><<<dim3(32,16,1), blk, 0, stream>>>(
        OlnHi, OlnLo, DIM, 0,0, W12hi, W12lo, DIM, 0,0, b12,
        nullptr, 0,0, x12, nullptr, 2048, 0,0, DIM, 1.f, 1);

    // 8: gate = silu(x1)*x2 -> bf16 hi/lo
    silu_mul<<<4096, blk, 0, stream>>>(x12, GHi, GLo);

    // 9: Oa = Oln + gate * W3^T + b3
    gemm_mfma<3,1,1,0><<<dim3(32,8,1), blk, 0, stream>>>(
        GHi, GLo, DIM, 0,0, W3hi, W3lo, DIM, 0,0, b3,
        Oln, 0,0, Oa, nullptr, DIM, 0,0, DIM, 1.f, 1);

    // 10: LN1 -> final O
    ln_rows<0><<<4096, blk, 0, stream>>>(Oa, g1, be1, Oout, nullptr, nullptr);
}

// Round 8
// 979.253 us; speedup vs baseline: 1.1901x; 1.1901x over previous
//
#include <hip/hip_runtime.h>
#include <math.h>

// Problem constants (reference: MAB block, B=4, N=1024, D=1024, H=16)
#define BATCH 4
#define NQL   1024
#define NKL   1024
#define DIM   1024
#define NHEAD 16
#define DHEAD 64
#define SCALE 0.03125f      // 1/sqrt(DIM)

typedef float  f32x4  __attribute__((ext_vector_type(4)));
typedef short  short8 __attribute__((ext_vector_type(8)));

__device__ __forceinline__ ushort f2bf(float x) {
    uint u = __float_as_uint(x);
    u += 0x7FFFu + ((u >> 16) & 1u);
    return (ushort)(u >> 16);
}
__device__ __forceinline__ float bf2f(ushort h) {
    return __uint_as_float(((uint)h) << 16);
}

// ===========================================================================
// split_bf: x (fp32) -> hi = bf16(x), lo = bf16(x - hi).  n4 = n/4.
// ===========================================================================
__global__ __launch_bounds__(256)
void split_bf(const float* __restrict__ x, ushort* __restrict__ hi,
              ushort* __restrict__ lo, int n4)
{
    const int i = blockIdx.x * 256 + threadIdx.x;
    if (i >= n4) return;
    const float4 v = ((const float4*)x)[i];
    ushort4 h, l;
    h.x = f2bf(v.x); l.x = f2bf(v.x - bf2f(h.x));
    h.y = f2bf(v.y); l.y = f2bf(v.y - bf2f(h.y));
    h.z = f2bf(v.z); l.z = f2bf(v.z - bf2f(h.z));
    h.w = f2bf(v.w); l.w = f2bf(v.w - bf2f(h.w));
    ((ushort4*)hi)[i] = h;
    ((ushort4*)lo)[i] = l;
}

// ===========================================================================
// gemm_mfma: C[m,n] = scale * sum_k A[m,k]*B[n,k]  (NT, bf16x3 split) + bias
// + optional residual. 128x128 tile, 4 waves, BK=32, mfma_f32_16x16x32_bf16.
// LDS row stride 40 bf16 (80B = 20 words): fragment ds_read_b128 across 16
// consecutive rows hits 8 distinct bank-quads -> 2-way (free), vs 8-way at
// stride 32. (Round-5 ran stride 32: LDS-bound ~300TF.)
// OMODE: 0 = fp32 C; 1 = fp32 C + bf16-hi copy; 2 = bf16-hi only;
//        3 = Vt only:  Vt[(h*4+b)][d][key] bf16  (b=r>>10,key=r&1023,
//            h=c>>6,d=c&63) — for the flash kernel's PV B-operand.
// C/D layout (validated on HW round 5): col=lane&15, row=(lane>>4)*4+reg.
// ===========================================================================
#define LDK 40

template<int NPROD, int BIAS, int RESID, int OMODE>
__global__ __launch_bounds__(256)
void gemm_mfma(const ushort* __restrict__ Ahi, const ushort* __restrict__ Alo,
               int lda,
               const ushort* __restrict__ Bhi, const ushort* __restrict__ Blo,
               int ldb,
               const float* __restrict__ bias,
               const float* __restrict__ rm,
               float* __restrict__ Cm, ushort* __restrict__ Chi,
               int ldc, int Kd, float scale)
{
    constexpr int NT_ = (NPROD == 3) ? 4 : 2;
    __shared__ ushort lds[2][NT_][128 * LDK];

    const int tid  = threadIdx.x;
    const int lane = tid & 63;
    const int wid  = tid >> 6;
    const int wr   = wid >> 1, wc = wid & 1;
    const int bm   = blockIdx.x * 128;
    const int bn   = blockIdx.y * 128;

    const ushort* tb[NT_];
    int tldv[NT_];
    tb[0] = Ahi + (size_t)bm * lda;  tldv[0] = lda;
    tb[1] = Bhi + (size_t)bn * ldb;  tldv[1] = ldb;
    if constexpr (NPROD == 3) {
        tb[2] = Alo + (size_t)bm * lda;  tldv[2] = lda;
        tb[3] = Blo + (size_t)bn * ldb;  tldv[3] = ldb;
    }

    int4 rg[NT_][2];
    auto gload = [&](int k0) {
#pragma unroll
        for (int tt = 0; tt < NT_; ++tt)
#pragma unroll
            for (int p = 0; p < 2; ++p) {
                const int idx = p * 256 + tid;           // 0..511 16B-chunks
                rg[tt][p] = *(const int4*)(tb[tt] + (size_t)(idx >> 2) * tldv[tt]
                                           + k0 + ((idx & 3) << 3));
            }
    };
    auto dswrite = [&](int buf) {
#pragma unroll
        for (int tt = 0; tt < NT_; ++tt)
#pragma unroll
            for (int p = 0; p < 2; ++p) {
                const int idx = p * 256 + tid;
                *(int4*)&lds[buf][tt][(idx >> 2) * LDK + ((idx & 3) << 3)] = rg[tt][p];
            }
    };

    gload(0);
    dswrite(0);
    __syncthreads();

    f32x4 acc[4][4] = {};
    int cur = 0;
    const int nt = Kd >> 5;

    const int rA = wr * 64 + (lane & 15);
    const int rB = wc * 64 + (lane & 15);
    const int kg = (lane >> 4) << 3;

    for (int t = 0; t < nt; ++t) {
        const bool more = (t + 1) < nt;
        if (more) gload((t + 1) << 5);

        short8 ah[4], bh[4], al[4], bl[4];
#pragma unroll
        for (int f = 0; f < 4; ++f) {
            ah[f] = *(const short8*)&lds[cur][0][(rA + f * 16) * LDK + kg];
            bh[f] = *(const short8*)&lds[cur][1][(rB + f * 16) * LDK + kg];
        }
        if constexpr (NPROD == 3) {
#pragma unroll
            for (int f = 0; f < 4; ++f) {
                al[f] = *(const short8*)&lds[cur][2][(rA + f * 16) * LDK + kg];
                bl[f] = *(const short8*)&lds[cur][3][(rB + f * 16) * LDK + kg];
            }
        }

#pragma unroll
        for (int fi = 0; fi < 4; ++fi)
#pragma unroll
            for (int fj = 0; fj < 4; ++fj) {
                acc[fi][fj] = __builtin_amdgcn_mfma_f32_16x16x32_bf16(ah[fi], bh[fj], acc[fi][fj], 0, 0, 0);
                if constexpr (NPROD == 3) {
                    acc[fi][fj] = __builtin_amdgcn_mfma_f32_16x16x32_bf16(ah[fi], bl[fj], acc[fi][fj], 0, 0, 0);
                    acc[fi][fj] = __builtin_amdgcn_mfma_f32_16x16x32_bf16(al[fi], bh[fj], acc[fi][fj], 0, 0, 0);
                }
            }

        if (more) dswrite(cur ^ 1);
        __syncthreads();
        cur ^= 1;
    }

    float biasv[4];
    if (BIAS) {
#pragma unroll
        for (int fj = 0; fj < 4; ++fj)
            biasv[fj] = bias[bn + wc * 64 + fj * 16 + (lane & 15)];
    }
#pragma unroll
    for (int fi = 0; fi < 4; ++fi) {
        const int r0 = bm + wr * 64 + fi * 16 + ((lane >> 4) << 2);
#pragma unroll
        for (int fj = 0; fj < 4; ++fj) {
            const int c = bn + wc * 64 + fj * 16 + (lane & 15);
            if constexpr (OMODE == 3) {
                ushort4 v4;
#pragma unroll
                for (int r = 0; r < 4; ++r) {
                    float o = acc[fi][fj][r] * scale;
                    if (BIAS) o += biasv[fj];
                    ((ushort*)&v4)[r] = f2bf(o);
                }
                const int b   = r0 >> 10;
                const int key = r0 & 1023;
                const int h   = c >> 6;
                const int d   = c & 63;
                *(ushort4*)(Chi + ((size_t)((h << 2) + b) << 16) + (size_t)d * 1024 + key) = v4;
            } else {
#pragma unroll
                for (int r = 0; r < 4; ++r) {
                    float o = acc[fi][fj][r] * scale;
                    if (BIAS) o += biasv[fj];
                    if (RESID) o += rm[(size_t)(r0 + r) * ldc + c];
                    if (OMODE == 0 || OMODE == 1)
                        Cm[(size_t)(r0 + r) * ldc + c] = o;
                    if (OMODE == 1 || OMODE == 2)
                        Chi[(size_t)(r0 + r) * ldc + c] = f2bf(o);
                }
            }
        }
    }
}

// ===========================================================================
// flash_attn: per block = 128 q-rows x one hb (h*4+b). grid (8, 64), 4 waves.
// Never materializes raw S.
//   pass 1: S = Q.K^T via MFMA (streamed K tiles of 64 keys), online
//           per-lane max/sum over the lane's key-columns; one cross-lane
//           (16-lane) reduce at the end -> row m, 1/l.
//   pass 2: recompute S, P = exp(S*SCALE - m)/l, write P straight to the
//           A output (only write of A), stash P bf16 in wave-private LDS,
//           PV via MFMA with V from pre-transposed Vt; O = Qp + P.V.
// Fragment conventions identical to the HW-validated gemm_mfma.
// ===========================================================================
__global__ __launch_bounds__(256)
void flash_attn(const ushort* __restrict__ QpHi,  // [4][1024][1024]
                const ushort* __restrict__ KpHi,  // [4][1024][1024]
                const ushort* __restrict__ Vt,    // [64][64][1024]
                const float*  __restrict__ Qp,    // [4][1024][1024] residual
                float* __restrict__ Aout,         // [64][1024][1024]
                float* __restrict__ Oa)           // [4][1024][1024]
{
    __shared__ ushort Ks[2][64][72];   // [key][dim], stride 72 -> 2-way banks
    __shared__ ushort Vs[2][64][72];   // [dim][key]
    __shared__ ushort Ps[4][32][72];   // per-wave P tile [q][key]

    const int tid  = threadIdx.x;
    const int lane = tid & 63;
    const int w    = tid >> 6;
    const int l15  = lane & 15;
    const int lg   = lane >> 4;          // 0..3
    const int bm   = blockIdx.x * 128;
    const int hb   = blockIdx.y;
    const int zh   = hb >> 2, zb = hb & 3;

    const ushort* Qb  = QpHi + ((size_t)zb << 20) + zh * 64;
    const ushort* Kb  = KpHi + ((size_t)zb << 20) + zh * 64;
    const ushort* Vtb = Vt   + ((size_t)hb << 16);
    const float*  Qrb = Qp   + ((size_t)zb << 20) + zh * 64 + (size_t)bm * DIM;
    float* Ab = Aout + ((size_t)hb << 20) + (size_t)bm * NKL;
    float* Ob = Oa   + ((size_t)zb << 20) + zh * 64 + (size_t)bm * DIM;

    // Q fragments, held in registers for the whole kernel
    short8 qf[2][2];
#pragma unroll
    for (int qg = 0; qg < 2; ++qg)
#pragma unroll
        for (int kg = 0; kg < 2; ++kg)
            qf[qg][kg] = *(const short8*)(Qb + (size_t)(bm + w * 32 + qg * 16 + l15) * DIM
                                          + kg * 32 + lg * 8);

    int4 kreg[2], vreg[2];
    auto kload = [&](int kt) {
#pragma unroll
        for (int p = 0; p < 2; ++p) {
            const int c = p * 256 + tid;           // key=c>>3, d8=c&7
            kreg[p] = *(const int4*)(Kb + (size_t)(kt * 64 + (c >> 3)) * DIM + (c & 7) * 8);
        }
    };
    auto kstore = [&](int buf) {
#pragma unroll
        for (int p = 0; p < 2; ++p) {
            const int c = p * 256 + tid;
            *(int4*)&Ks[buf][c >> 3][(c & 7) * 8] = kreg[p];
        }
    };
    auto vload = [&](int kt) {
#pragma unroll
        for (int p = 0; p < 2; ++p) {
            const int c = p * 256 + tid;           // d=c>>3, k8=c&7
            vreg[p] = *(const int4*)(Vtb + (size_t)(c >> 3) * 1024 + kt * 64 + (c & 7) * 8);
        }
    };
    auto vstore = [&](int buf) {
#pragma unroll
        for (int p = 0; p < 2; ++p) {
            const int c = p * 256 + tid;
            *(int4*)&Vs[buf][c >> 3][(c & 7) * 8] = vreg[p];
        }
    };
    auto qk = [&](int buf, f32x4 (*s)[4]) {
        short8 kf[4][2];
#pragma unroll
        for (int cg = 0; cg < 4; ++cg)
#pragma unroll
            for (int kg = 0; kg < 2; ++kg)
                kf[cg][kg] = *(const short8*)&Ks[buf][cg * 16 + l15][kg * 32 + lg * 8];
#pragma unroll
        for (int qg = 0; qg < 2; ++qg)
#pragma unroll
            for (int cg = 0; cg < 4; ++cg) {
                s[qg][cg] = __builtin_amdgcn_mfma_f32_16x16x32_bf16(qf[qg][0], kf[cg][0], s[qg][cg], 0, 0, 0);
                s[qg][cg] = __builtin_amdgcn_mfma_f32_16x16x32_bf16(qf[qg][1], kf[cg][1], s[qg][cg], 0, 0, 0);
            }
    };

    // ---- pass 1: online per-lane stats ------------------------------------
    float mrun[2][4], lrun[2][4];
#pragma unroll
    for (int qg = 0; qg < 2; ++qg)
#pragma unroll
        for (int r = 0; r < 4; ++r) { mrun[qg][r] = -INFINITY; lrun[qg][r] = 0.f; }

    kload(0); kstore(0); __syncthreads();
    for (int kt = 0; kt < 16; ++kt) {
        const bool more = kt < 15;
        if (more) kload(kt + 1);
        f32x4 s[2][4] = {};
        qk(kt & 1, s);
#pragma unroll
        for (int qg = 0; qg < 2; ++qg)
#pragma unroll
            for (int r = 0; r < 4; ++r) {
                const float v0 = s[qg][0][r] * SCALE, v1 = s[qg][1][r] * SCALE;
                const float v2 = s[qg][2][r] * SCALE, v3 = s[qg][3][r] * SCALE;
                const float tm = fmaxf(fmaxf(v0, v1), fmaxf(v2, v3));
                const float mn = fmaxf(mrun[qg][r], tm);
                const float sc = __expf(mrun[qg][r] - mn);
                lrun[qg][r] = lrun[qg][r] * sc
                            + __expf(v0 - mn) + __expf(v1 - mn)
                            + __expf(v2 - mn) + __expf(v3 - mn);
                mrun[qg][r] = mn;
            }
        if (more) { kstore((kt + 1) & 1); __syncthreads(); }
    }

    // cross-lane (16-lane key groups) finalize
    float mf[2][4], li[2][4];
#pragma unroll
    for (int qg = 0; qg < 2; ++qg)
#pragma unroll
        for (int r = 0; r < 4; ++r) {
            float m = mrun[qg][r];
#pragma unroll
            for (int off = 1; off < 16; off <<= 1) m = fmaxf(m, __shfl_xor(m, off));
            float lv = lrun[qg][r] * __expf(mrun[qg][r] - m);
#pragma unroll
            for (int off = 1; off < 16; off <<= 1) lv += __shfl_xor(lv, off);
            mf[qg][r] = m;
            li[qg][r] = 1.f / lv;
        }

    // ---- pass 2: A write + PV ---------------------------------------------
    kload(0); vload(0);
    __syncthreads();            // all pass-1 LDS reads done
    kstore(0); vstore(0);
    __syncthreads();

    f32x4 oacc[2][4] = {};
    for (int kt = 0; kt < 16; ++kt) {
        const bool more = kt < 15;
        if (more) { kload(kt + 1); vload(kt + 1); }
        f32x4 s[2][4] = {};
        qk(kt & 1, s);

#pragma unroll
        for (int qg = 0; qg < 2; ++qg)
#pragma unroll
            for (int cg = 0; cg < 4; ++cg) {
#pragma unroll
                for (int r = 0; r < 4; ++r) {
                    const float p = __expf(s[qg][cg][r] * SCALE - mf[qg][r]) * li[qg][r];
                    Ps[w][qg * 16 + lg * 4 + r][cg * 16 + l15] = f2bf(p);
                    Ab[(size_t)(w * 32 + qg * 16 + lg * 4 + r) * NKL
                       + kt * 64 + cg * 16 + l15] = p;
                }
            }

        short8 pf[2][2], vf[4][2];
#pragma unroll
        for (int qg = 0; qg < 2; ++qg)
#pragma unroll
            for (int kk = 0; kk < 2; ++kk)
                pf[qg][kk] = *(const short8*)&Ps[w][qg * 16 + l15][kk * 32 + lg * 8];
#pragma unroll
        for (int dg = 0; dg < 4; ++dg)
#pragma unroll
            for (int kk = 0; kk < 2; ++kk)
                vf[dg][kk] = *(const short8*)&Vs[kt & 1][dg * 16 + l15][kk * 32 + lg * 8];
#pragma unroll
        for (int qg = 0; qg < 2; ++qg)
#pragma unroll
            for (int dg = 0; dg < 4; ++dg) {
                oacc[qg][dg] = __builtin_amdgcn_mfma_f32_16x16x32_bf16(pf[qg][0], vf[dg][0], oacc[qg][dg], 0, 0, 0);
                oacc[qg][dg] = __builtin_amdgcn_mfma_f32_16x16x32_bf16(pf[qg][1], vf[dg][1], oacc[qg][dg], 0, 0, 0);
            }

        if (more) { kstore((kt + 1) & 1); vstore((kt + 1) & 1); __syncthreads(); }
    }

    // epilogue: O = Qp + P.V
#pragma unroll
    for (int qg = 0; qg < 2; ++qg)
#pragma unroll
        for (int dg = 0; dg < 4; ++dg)
#pragma unroll
            for (int r = 0; r < 4; ++r) {
                const size_t idx = (size_t)(w * 32 + qg * 16 + lg * 4 + r) * DIM
                                 + dg * 16 + l15;
                Ob[idx] = oacc[qg][dg][r] + Qrb[idx];
            }
}

// ===========================================================================
// Row LayerNorm (1024 cols, one block/row). SPLIT=1 also emits bf16 hi/lo.
// ===========================================================================
template<int SPLIT>
__global__ __launch_bounds__(256)
void ln_rows(const float* __restrict__ in, const float* __restrict__ g,
             const float* __restrict__ b, float* __restrict__ out,
             ushort* __restrict__ ohi, ushort* __restrict__ olo)
{
    const int row = blockIdx.x;
    const int tid = threadIdx.x;
    const float4 xv = *(const float4*)(in + (size_t)row * DIM + (tid << 2));

    float s = xv.x + xv.y + xv.z + xv.w;
    float q = xv.x * xv.x + xv.y * xv.y + xv.z * xv.z + xv.w * xv.w;
#pragma unroll
    for (int off = 32; off; off >>= 1) {
        s += __shfl_xor(s, off);
        q += __shfl_xor(q, off);
    }
    __shared__ float ss[4], qq[4];
    if ((tid & 63) == 0) { ss[tid >> 6] = s; qq[tid >> 6] = q; }
    __syncthreads();
    s = ss[0] + ss[1] + ss[2] + ss[3];
    q = qq[0] + qq[1] + qq[2] + qq[3];

    const float mu  = s * (1.f / 1024.f);
    const float var = q * (1.f / 1024.f) - mu * mu;
    const float rs  = rsqrtf(var + 1e-5f);

    const float4 gv = *(const float4*)(g + (tid << 2));
    const float4 bv = *(const float4*)(b + (tid << 2));
    float4 o;
    o.x = (xv.x - mu) * rs * gv.x + bv.x;
    o.y = (xv.y - mu) * rs * gv.y + bv.y;
    o.z = (xv.z - mu) * rs * gv.z + bv.z;
    o.w = (xv.w - mu) * rs * gv.w + bv.w;
    *(float4*)(out + (size_t)row * DIM + (tid << 2)) = o;

    if (SPLIT) {
        ushort4 h, l;
        h.x = f2bf(o.x); l.x = f2bf(o.x - bf2f(h.x));
        h.y = f2bf(o.y); l.y = f2bf(o.y - bf2f(h.y));
        h.z = f2bf(o.z); l.z = f2bf(o.z - bf2f(h.z));
        h.w = f2bf(o.w); l.w = f2bf(o.w - bf2f(h.w));
        ((ushort4*)(ohi + (size_t)row * DIM))[tid] = h;
        ((ushort4*)(olo + (size_t)row * DIM))[tid] = l;
    }
}

// ===========================================================================
// gate = silu(x1) * x2, emitted as bf16 hi/lo split.
// ===========================================================================
__global__ __launch_bounds__(256)
void silu_mul(const float* __restrict__ x12, ushort* __restrict__ ghi,
              ushort* __restrict__ glo)
{
    const int i = blockIdx.x * 256 + threadIdx.x;
    const int n = i >> 8;
    const int c = (i & 255) << 2;
    const float4 a = *(const float4*)(x12 + (size_t)n * 2048 + c);
    const float4 b = *(const float4*)(x12 + (size_t)n * 2048 + 1024 + c);
    float4 o;
    o.x = a.x / (1.f + __expf(-a.x)) * b.x;
    o.y = a.y / (1.f + __expf(-a.y)) * b.y;
    o.z = a.z / (1.f + __expf(-a.z)) * b.z;
    o.w = a.w / (1.f + __expf(-a.w)) * b.w;
    ushort4 h, l;
    h.x = f2bf(o.x); l.x = f2bf(o.x - bf2f(h.x));
    h.y = f2bf(o.y); l.y = f2bf(o.y - bf2f(h.y));
    h.z = f2bf(o.z); l.z = f2bf(o.z - bf2f(h.z));
    h.w = f2bf(o.w); l.w = f2bf(o.w - bf2f(h.w));
    ((ushort4*)ghi)[i] = h;
    ((ushort4*)glo)[i] = l;
}

// ---------------------------------------------------------------------------
extern "C" void kernel_launch(void* const* d_in, const int* in_sizes, int n_in,
                              void* d_out, int out_size, void* d_ws, size_t ws_size,
                              hipStream_t stream)
{
    const float* Q   = (const float*)d_in[0];
    const float* K   = (const float*)d_in[1];
    const float* Wq  = (const float*)d_in[2];
    const float* bq  = (const float*)d_in[3];
    const float* Wk  = (const float*)d_in[4];
    const float* bk  = (const float*)d_in[5];
    const float* Wv  = (const float*)d_in[6];
    const float* bv  = (const float*)d_in[7];
    const float* g0  = (const float*)d_in[8];
    const float* be0 = (const float*)d_in[9];
    const float* g1  = (const float*)d_in[10];
    const float* be1 = (const float*)d_in[11];
    const float* W12 = (const float*)d_in[12];
    const float* b12 = (const float*)d_in[13];
    const float* W3  = (const float*)d_in[14];
    const float* b3  = (const float*)d_in[15];

    // fp32 region (80 MB): Qp, Oa, Oln, x12(32MB)
    float* ws   = (float*)d_ws;
    float* Qp   = ws;                    // [4096,1024]
    float* Oa   = ws + (1u << 22);
    float* Oln  = ws + (2u << 22);
    float* x12  = ws + (3u << 22);       // [4096,2048] (32 MB)

    // attention-proj weight splits overlay x12 (dead until FFN)
    ushort* wsm   = (ushort*)(ws + (3u << 22));
    ushort* Wqhi  = wsm;                 // 1M us each
    ushort* Wqlo  = wsm + (1u << 20);
    ushort* Wkhi  = wsm + (2u << 20);
    ushort* Wklo  = wsm + (3u << 20);
    ushort* Wvhi  = wsm + (4u << 20);
    ushort* Wvlo  = wsm + (5u << 20);

    // ushort region after fp32 (slots of 4M us = 8 MB)
    ushort* u     = (ushort*)(ws + (5u << 22));
    ushort* QpHi  = u;                   // s0
    ushort* KpHi  = u + (1u << 22);      // s1
    ushort* Qhi   = u + (2u << 22);      // s2
    ushort* Qlo   = u + (3u << 22);      // s3
    ushort* Khi   = u + (4u << 22);      // s4
    ushort* Klo   = u + (5u << 22);      // s5
    ushort* Vt    = u + (6u << 22);      // s6  [64][64][1024]
    ushort* OlnHi = Qhi;                 // reuse (dead after Q-proj)
    ushort* OlnLo = Qlo;
    ushort* GHi   = Khi;                 // reuse (dead after V-proj)
    ushort* GLo   = Klo;
    ushort* W12hi = u + (7u << 22);      // 2M us
    ushort* W12lo = W12hi + (1u << 21);
    ushort* W3hi  = W12hi + (2u << 21);  // 1M us
    ushort* W3lo  = W12hi + (3u << 21);
    // total: 80 + 56 + 12 = 148 MB  (round-5 used 152 MB OK)

    float* Oout = (float*)d_out;                 // [4,1024,1024]
    float* Aout = Oout + (1u << 22);             // [64,1024,1024]

    const dim3 blk(256);

    // 0: splits
    split_bf<<<4096, blk, 0, stream>>>(Q,   Qhi,   Qlo,   1 << 20);
    split_bf<<<4096, blk, 0, stream>>>(K,   Khi,   Klo,   1 << 20);
    split_bf<<<1024, blk, 0, stream>>>(Wq,  Wqhi,  Wqlo,  1 << 18);
    split_bf<<<1024, blk, 0, stream>>>(Wk,  Wkhi,  Wklo,  1 << 18);
    split_bf<<<1024, blk, 0, stream>>>(Wv,  Wvhi,  Wvlo,  1 << 18);
    split_bf<<<2048, blk, 0, stream>>>(W12, W12hi, W12lo, 1 << 19);
    split_bf<<<1024, blk, 0, stream>>>(W3,  W3hi,  W3lo,  1 << 18);

    // 1-3: projections. Q -> fp32 + hi; K -> hi only; V -> transposed bf16 Vt.
    gemm_mfma<3,1,0,1><<<dim3(32,8), blk, 0, stream>>>(
        Qhi, Qlo, DIM, Wqhi, Wqlo, DIM, bq, nullptr, Qp, QpHi, DIM, DIM, 1.f);
    gemm_mfma<3,1,0,2><<<dim3(32,8), blk, 0, stream>>>(
        Khi, Klo, DIM, Wkhi, Wklo, DIM, bk, nullptr, nullptr, KpHi, DIM, DIM, 1.f);
    gemm_mfma<3,1,0,3><<<dim3(32,8), blk, 0, stream>>>(
        Khi, Klo, DIM, Wvhi, Wvlo, DIM, bv, nullptr, nullptr, Vt, DIM, DIM, 1.f);

    // 4: flash attention: writes A (d_out) once + Oa = Qp + P.V
    flash_attn<<<dim3(8,64), blk, 0, stream>>>(QpHi, KpHi, Vt, Qp, Aout, Oa);

    // 5: LN0 (+ bf16 split for FFN)
    ln_rows<1><<<4096, blk, 0, stream>>>(Oa, g0, be0, Oln, OlnHi, OlnLo);

    // 6: x12 = Oln * W12^T + b12
    gemm_mfma<3,1,0,0><<<dim3(32,16), blk, 0, stream>>>(
        OlnHi, OlnLo, DIM, W12hi, W12lo, DIM, b12, nullptr, x12, nullptr, 2048, DIM, 1.f);

    // 7: gate = silu(x1)*x2 -> bf16 hi/lo
    silu_mul<<<4096, blk, 0, stream>>>(x12, GHi, GLo);

    // 8: Oa = Oln + gate * W3^T + b3
    gemm_mfma<3,1,1,0><<<dim3(32,8), blk, 0, stream>>>(
        GHi, GLo, DIM, W3hi, W3lo, DIM, b3, Oln, Oa, nullptr, DIM, DIM, 1.f);

    // 9: LN1 -> final O
    ln_rows<0><<<4096, blk, 0, stream>>>(Oa, g1, be1, Oout, nullptr, nullptr);
}